// Round 1
// baseline (1534.093 us; speedup 1.0000x reference)
//
#include <hip/hip_runtime.h>
#include <stdint.h>

#define H 512
#define KAUG 544
#define KT_N 34            // K tiles of 16 (544/16)
#define NT_N 64            // N tiles of 32 (2048/32)
#define LROW 552           // LDS row stride in shorts (16B aligned, 2-way bank alias = free)
#define NROW 32
#define WMAT_ELEMS (NT_N * KT_N * 512)   // 64*34*512 = 1,114,112 bf16 per matrix
#define T_DEC 32
#define B_TOT 4096

typedef __attribute__((ext_vector_type(8))) short short8;
typedef __attribute__((ext_vector_type(16))) float floatx16;

__device__ __forceinline__ unsigned short f2bf(float x) {
  union { float f; unsigned int u; } v; v.f = x;
  unsigned int u = v.u;
  return (unsigned short)((u + 0x7FFFu + ((u >> 16) & 1u)) >> 16);
}
__device__ __forceinline__ float bf2f(unsigned short s) {
  union { unsigned int u; float f; } v; v.u = ((unsigned int)s) << 16;
  return v.f;
}
__device__ __forceinline__ float sigm(float x) { return 1.0f / (1.0f + __expf(-x)); }
__device__ __forceinline__ float tanh_f(float x) {
  return 2.0f / (1.0f + __expf(-2.0f * x)) - 1.0f;
}

// ---------------- prep: build augmented tile-packed bf16 weights -------------
// W_aug[n][ka]: ka<512 -> Wh[n][ka]; 512..515 -> Wi[n][ka-512]; 516 -> b[n]; else 0
// packed element index: ((nt*34 + kt)*64 + lane)*8 + ks  with
//   nt=n>>5, ni=n&31, kt=ka>>4, kh=(ka>>3)&1, ks=ka&7, lane=kh*32+ni
__global__ void prep_weights(
    const float* __restrict__ Wh_s, const float* __restrict__ Wi_s, const float* __restrict__ b_s,
    const float* __restrict__ Wh_p, const float* __restrict__ Wi_p, const float* __restrict__ b_p,
    const float* __restrict__ Wh_d, const float* __restrict__ Wi_d, const float* __restrict__ b_d,
    const float* __restrict__ Wh_i, const float* __restrict__ Wi_i, const float* __restrict__ b_i,
    short* __restrict__ wpack)
{
  int idx = blockIdx.x * 256 + threadIdx.x;
  const int per = 2048 * KAUG;
  if (idx >= 4 * per) return;
  int mat = idx / per;
  int rem = idx - mat * per;
  int n = rem / KAUG;
  int ka = rem - n * KAUG;
  const float* Wh; const float* Wi; const float* bb;
  if (mat == 0)      { Wh = Wh_s; Wi = Wi_s; bb = b_s; }
  else if (mat == 1) { Wh = Wh_p; Wi = Wi_p; bb = b_p; }
  else if (mat == 2) { Wh = Wh_d; Wi = Wi_d; bb = b_d; }
  else               { Wh = Wh_i; Wi = Wi_i; bb = b_i; }
  float v;
  if (ka < 512)      v = Wh[n * 512 + ka];
  else if (ka < 516) v = Wi[n * 4 + (ka - 512)];
  else if (ka == 516) v = bb[n];
  else               v = 0.0f;
  int nt = n >> 5, ni = n & 31;
  int kt = ka >> 4, kh = (ka >> 3) & 1, ks = ka & 7;
  int lanep = kh * 32 + ni;
  wpack[(size_t)mat * WMAT_ELEMS + ((((size_t)nt * KT_N + kt) * 64 + lanep) << 3) + ks] =
      (short)f2bf(v);
}

// ---------------- one LSTM step: gates = h_aug @ W_aug.T, then cell update ---
// wave wv owns j-cols [wv*64, wv*64+64); computes all 4 gates for that slice.
__device__ __forceinline__ void lstm_step_mfma(
    const short* hl, const short* __restrict__ wm,
    int lane, int wv, float c_reg[2][16], float hnew[2][16])
{
  int arow = lane & 31, ahalf = lane >> 5;
  const short* aptr = hl + arow * LROW + ahalf * 8;
  #pragma unroll
  for (int jt = 0; jt < 2; ++jt) {
    int ntbase = wv * 2 + jt;
    const short* bp0 = wm + (((size_t)(0 * 16 + ntbase) * KT_N) << 9) + (lane << 3);
    const short* bp1 = wm + (((size_t)(1 * 16 + ntbase) * KT_N) << 9) + (lane << 3);
    const short* bp2 = wm + (((size_t)(2 * 16 + ntbase) * KT_N) << 9) + (lane << 3);
    const short* bp3 = wm + (((size_t)(3 * 16 + ntbase) * KT_N) << 9) + (lane << 3);
    floatx16 ai = (floatx16)0.0f, af = (floatx16)0.0f, ag = (floatx16)0.0f, ao = (floatx16)0.0f;
    #pragma unroll 2
    for (int kt = 0; kt < KT_N; ++kt) {
      short8 a  = *(const short8*)(aptr + kt * 16);
      short8 b0 = *(const short8*)(bp0 + (kt << 9));
      short8 b1 = *(const short8*)(bp1 + (kt << 9));
      short8 b2 = *(const short8*)(bp2 + (kt << 9));
      short8 b3 = *(const short8*)(bp3 + (kt << 9));
      ai = __builtin_amdgcn_mfma_f32_32x32x16_bf16(a, b0, ai, 0, 0, 0);
      af = __builtin_amdgcn_mfma_f32_32x32x16_bf16(a, b1, af, 0, 0, 0);
      ag = __builtin_amdgcn_mfma_f32_32x32x16_bf16(a, b2, ag, 0, 0, 0);
      ao = __builtin_amdgcn_mfma_f32_32x32x16_bf16(a, b3, ao, 0, 0, 0);
    }
    #pragma unroll
    for (int r = 0; r < 16; ++r) {
      float si = sigm(ai[r]);
      float sf = sigm(af[r]);
      float tg = tanh_f(ag[r]);
      float so = sigm(ao[r]);
      float cn = sf * c_reg[jt][r] + si * tg;
      c_reg[jt][r] = cn;
      hnew[jt][r] = so * tanh_f(cn);
    }
  }
}

__device__ __forceinline__ void write_h(short* hl, int lane, int wv, const float hnew[2][16]) {
  int arow = lane & 31, ahalf = lane >> 5;
  #pragma unroll
  for (int jt = 0; jt < 2; ++jt) {
    int col = wv * 64 + jt * 32 + arow;
    #pragma unroll
    for (int r = 0; r < 16; ++r) {
      int row = (r & 3) + ((r >> 2) << 3) + (ahalf << 2);
      hl[row * LROW + col] = (short)f2bf(hnew[jt][r]);
    }
  }
}

// ---------------- encoder: blocks 0..255 -> (enc, row-group) via XCD swizzle --
__global__ __launch_bounds__(512) void lstm_encoder(
    const float* __restrict__ speed, const float* __restrict__ pos,
    const short* __restrict__ wpack,
    short* __restrict__ h_enc, float* __restrict__ c_enc)
{
  __shared__ short hl[NROW * LROW];
  int tid = threadIdx.x;
  int b = blockIdx.x;
  int xcd = b & 7, slot = b >> 3;
  int enc = xcd >> 2;               // XCDs 0-3: speed, 4-7: pos (L2 locality)
  int rg = slot * 4 + (xcd & 3);    // 0..127
  int r0 = rg * 32;
  const float* xin = enc ? pos : speed;
  const short* wm = wpack + (size_t)enc * WMAT_ELEMS;

  for (int i = tid; i < NROW * LROW; i += 512) hl[i] = 0;
  __syncthreads();
  if (tid < 32) hl[tid * LROW + 516] = (short)0x3F80;   // bias lane = 1.0
  if (tid < 128) {
    int r = tid >> 2, c = tid & 3;
    hl[r * LROW + 512 + c] = (short)f2bf(xin[(r0 + r) * 64 + c]);   // x_0
  }
  __syncthreads();

  int lane = tid & 63, wv = tid >> 6;
  float c_reg[2][16];
  #pragma unroll
  for (int jt = 0; jt < 2; ++jt)
    #pragma unroll
    for (int r = 0; r < 16; ++r) c_reg[jt][r] = 0.0f;
  float hnew[2][16];

  for (int t = 0; t < 16; ++t) {
    lstm_step_mfma(hl, wm, lane, wv, c_reg, hnew);
    __syncthreads();
    write_h(hl, lane, wv, hnew);
    if (t < 15 && tid < 128) {
      int r = tid >> 2, c = tid & 3;
      hl[r * LROW + 512 + c] = (short)f2bf(xin[(r0 + r) * 64 + (t + 1) * 4 + c]);
    }
    __syncthreads();
  }

  // store h (bf16) + c (fp32) for the decoder
  for (int i = tid; i < 32 * 512; i += 512) {
    int r = i >> 9, k = i & 511;
    h_enc[((size_t)(enc * B_TOT + r0 + r) << 9) + k] = hl[r * LROW + k];
  }
  int arow = lane & 31, ahalf = lane >> 5;
  #pragma unroll
  for (int jt = 0; jt < 2; ++jt) {
    int col = wv * 64 + jt * 32 + arow;
    #pragma unroll
    for (int r = 0; r < 16; ++r) {
      int row = (r & 3) + ((r >> 2) << 3) + (ahalf << 2);
      c_enc[((size_t)(enc * B_TOT + r0 + row) << 9) + col] = c_reg[jt][r];
    }
  }
}

// ---------------- decoder: chain 0 = speed head, chain 1 = crossing head -----
__global__ __launch_bounds__(512) void lstm_decoder(
    const float* __restrict__ speed, const float* __restrict__ pos,
    const short* __restrict__ wpack,
    const short* __restrict__ h_enc, const float* __restrict__ c_enc,
    const float* __restrict__ W_fs, const float* __restrict__ b_fs,
    const float* __restrict__ W_fc, const float* __restrict__ b_fc,
    const float* __restrict__ W_emb, const float* __restrict__ b_emb,
    float* __restrict__ out)
{
  __shared__ short hl[NROW * LROW];
  int tid = threadIdx.x;
  int b = blockIdx.x;
  int xcd = b & 7, slot = b >> 3;
  int chain = xcd >> 2;
  int rg = slot * 4 + (xcd & 3);
  int r0 = rg * 32;
  const short* wm = wpack + (size_t)(2 + chain) * WMAT_ELEMS;

  for (int i = tid; i < NROW * LROW; i += 512) hl[i] = 0;
  __syncthreads();
  for (int i = tid; i < 32 * 512; i += 512) {
    int r = i >> 9, k = i & 511;
    float h0 = bf2f((unsigned short)h_enc[((size_t)(r0 + r) << 9) + k])
             + bf2f((unsigned short)h_enc[((size_t)(B_TOT + r0 + r) << 9) + k]);
    hl[r * LROW + k] = (short)f2bf(h0);
  }
  if (tid < 32) hl[tid * LROW + 516] = (short)0x3F80;
  {
    const float* last = chain ? pos : speed;
    if (tid < 128) {
      int r = tid >> 2, c = tid & 3;
      hl[r * LROW + 512 + c] = (short)f2bf(last[(r0 + r) * 64 + 60 + c]); // x[:,15,:]
    }
  }
  int lane = tid & 63, wv = tid >> 6;
  int arow = lane & 31, ahalf = lane >> 5;
  float c_reg[2][16];
  #pragma unroll
  for (int jt = 0; jt < 2; ++jt) {
    int col = wv * 64 + jt * 32 + arow;
    #pragma unroll
    for (int r = 0; r < 16; ++r) {
      int row = (r & 3) + ((r >> 2) << 3) + (ahalf << 2);
      size_t gi = ((size_t)(r0 + row) << 9) + col;
      c_reg[jt][r] = c_enc[gi] + c_enc[gi + (((size_t)B_TOT) << 9)];
    }
  }
  __syncthreads();

  // preload head weights (per-lane 8-elem slice of each output row)
  float wro[4][8];
  float hb[4];
  float we[8], be[4];
  if (chain == 0) {
    #pragma unroll
    for (int o = 0; o < 4; ++o) {
      #pragma unroll
      for (int j = 0; j < 8; ++j) wro[o][j] = W_fs[o * 512 + lane * 8 + j];
      hb[o] = b_fs[o];
    }
  } else {
    #pragma unroll
    for (int o = 0; o < 2; ++o) {
      #pragma unroll
      for (int j = 0; j < 8; ++j) wro[o][j] = W_fc[o * 512 + lane * 8 + j];
      hb[o] = b_fc[o];
    }
    #pragma unroll
    for (int j = 0; j < 8; ++j) we[j] = W_emb[j];
    #pragma unroll
    for (int o = 0; o < 4; ++o) be[o] = b_emb[o];
  }

  float hnew[2][16];
  for (int t = 0; t < T_DEC; ++t) {
    lstm_step_mfma(hl, wm, lane, wv, c_reg, hnew);
    __syncthreads();
    write_h(hl, lane, wv, hnew);
    __syncthreads();
    // heads: wave wv handles rows [wv*4, wv*4+4); 64 lanes x 8 k-elems = 512
    #pragma unroll 1
    for (int r = 0; r < 4; ++r) {
      int row = wv * 4 + r;
      const short8 hvs = *(const short8*)(hl + row * LROW + lane * 8);
      float hv[8];
      #pragma unroll
      for (int j = 0; j < 8; ++j) hv[j] = bf2f((unsigned short)hvs[j]);
      if (chain == 0) {
        float p0 = 0.f, p1 = 0.f, p2 = 0.f, p3 = 0.f;
        #pragma unroll
        for (int j = 0; j < 8; ++j) {
          p0 += hv[j] * wro[0][j];
          p1 += hv[j] * wro[1][j];
          p2 += hv[j] * wro[2][j];
          p3 += hv[j] * wro[3][j];
        }
        #pragma unroll
        for (int off = 32; off > 0; off >>= 1) {
          p0 += __shfl_xor(p0, off);
          p1 += __shfl_xor(p1, off);
          p2 += __shfl_xor(p2, off);
          p3 += __shfl_xor(p3, off);
        }
        float s0 = fminf(fmaxf(p0 + hb[0], -100.0f), 100.0f);
        float s1 = fminf(fmaxf(p1 + hb[1], -100.0f), 100.0f);
        float s2 = fminf(fmaxf(p2 + hb[2], -100.0f), 100.0f);
        float s3 = fminf(fmaxf(p3 + hb[3], -100.0f), 100.0f);
        if (lane < 4) {
          float v = (lane == 0) ? s0 : (lane == 1) ? s1 : (lane == 2) ? s2 : s3;
          out[(size_t)(r0 + row) * 128 + t * 4 + lane] = v;       // speed_outputs
          hl[row * LROW + 512 + lane] = (short)f2bf(v);           // ls feedback
        }
      } else {
        float p0 = 0.f, p1 = 0.f;
        #pragma unroll
        for (int j = 0; j < 8; ++j) {
          p0 += hv[j] * wro[0][j];
          p1 += hv[j] * wro[1][j];
        }
        #pragma unroll
        for (int off = 32; off > 0; off >>= 1) {
          p0 += __shfl_xor(p0, off);
          p1 += __shfl_xor(p1, off);
        }
        float it0 = fmaxf(p0 + hb[0], 0.0f);
        float it1 = fmaxf(p1 + hb[1], 0.0f);
        if (lane < 4) {
          float lp = fmaxf(we[lane * 2] * it0 + we[lane * 2 + 1] * it1 + be[lane], 0.0f);
          hl[row * LROW + 512 + lane] = (short)f2bf(lp);          // lp feedback
        }
        if (t == T_DEC - 1 && lane < 2) {
          float m = fmaxf(it0, it1);
          float e0 = __expf(it0 - m), e1 = __expf(it1 - m);
          float v = ((lane == 0) ? e0 : e1) / (e0 + e1);
          out[(size_t)524288 + (size_t)(r0 + row) * 2 + lane] = v; // crossing
        }
      }
    }
    __syncthreads();
  }
}

extern "C" void kernel_launch(void* const* d_in, const int* in_sizes, int n_in,
                              void* d_out, int out_size, void* d_ws, size_t ws_size,
                              hipStream_t stream)
{
  const float* speed    = (const float*)d_in[0];
  const float* pos      = (const float*)d_in[1];
  const float* enc_s_Wi = (const float*)d_in[2];
  const float* enc_s_Wh = (const float*)d_in[3];
  const float* enc_s_b  = (const float*)d_in[4];
  const float* enc_p_Wi = (const float*)d_in[5];
  const float* enc_p_Wh = (const float*)d_in[6];
  const float* enc_p_b  = (const float*)d_in[7];
  const float* dec_s_Wi = (const float*)d_in[8];
  const float* dec_s_Wh = (const float*)d_in[9];
  const float* dec_s_b  = (const float*)d_in[10];
  const float* dec_i_Wi = (const float*)d_in[11];
  const float* dec_i_Wh = (const float*)d_in[12];
  const float* dec_i_b  = (const float*)d_in[13];
  const float* W_fs     = (const float*)d_in[14];
  const float* b_fs     = (const float*)d_in[15];
  const float* W_fc     = (const float*)d_in[16];
  const float* b_fc     = (const float*)d_in[17];
  const float* W_emb    = (const float*)d_in[18];
  const float* b_emb    = (const float*)d_in[19];
  float* out = (float*)d_out;

  char* ws = (char*)d_ws;
  short* wpack = (short*)ws;                 // 4 x 2,228,224 B = 8,912,896 B
  short* h_enc = (short*)(ws + 8912896);     // 2 x 4096 x 512 bf16 = 8,388,608 B
  float* c_enc = (float*)(ws + 17301504);    // 2 x 4096 x 512 f32  = 16,777,216 B

  prep_weights<<<17408, 256, 0, stream>>>(
      enc_s_Wh, enc_s_Wi, enc_s_b,
      enc_p_Wh, enc_p_Wi, enc_p_b,
      dec_s_Wh, dec_s_Wi, dec_s_b,
      dec_i_Wh, dec_i_Wi, dec_i_b,
      wpack);
  lstm_encoder<<<256, 512, 0, stream>>>(speed, pos, wpack, h_enc, c_enc);
  lstm_decoder<<<256, 512, 0, stream>>>(speed, pos, wpack, h_enc, c_enc,
                                        W_fs, b_fs, W_fc, b_fc, W_emb, b_emb, out);
}

// Round 2
// 1314.792 us; speedup vs baseline: 1.1668x; 1.1668x over previous
//
#include <hip/hip_runtime.h>
#include <stdint.h>

#define H 512
#define KAUG 528
#define KT_N 33            // K tiles of 16 (528/16)
#define LROW 536           // LDS row stride in shorts (16B aligned, 2-way bank alias = free)
#define NROW 32
#define WMAT_ELEMS (16 * KT_N * 4 * 512)   // 16 ntL * 33 kt * 4 gates * 512 = 1,081,344
#define T_DEC 32
#define B_TOT 4096

typedef __attribute__((ext_vector_type(8))) short short8;
typedef __attribute__((ext_vector_type(16))) float floatx16;

__device__ __forceinline__ unsigned short f2bf(float x) {
  union { float f; unsigned int u; } v; v.f = x;
  unsigned int u = v.u;
  return (unsigned short)((u + 0x7FFFu + ((u >> 16) & 1u)) >> 16);
}
__device__ __forceinline__ float bf2f(unsigned short s) {
  union { unsigned int u; float f; } v; v.u = ((unsigned int)s) << 16;
  return v.f;
}
__device__ __forceinline__ float rcpf(float x) { return __builtin_amdgcn_rcpf(x); }
// sigmoid via native v_exp + v_rcp (no IEEE div sequence)
__device__ __forceinline__ float sigm(float x) { return rcpf(1.0f + __expf(-x)); }
// tanh(x) = 1 - 2*sigmoid(-2x) -> one exp + one rcp
__device__ __forceinline__ float tanh_f(float x) {
  return 1.0f - 2.0f * rcpf(1.0f + __expf(2.0f * x));
}

// ---------------- prep: build augmented tile-packed bf16 weights -------------
// W_aug[n][ka]: ka<512 -> Wh[n][ka]; 512..515 -> Wi[n][ka-512]; 516 -> b[n]; else 0
// Layout (gate-contiguous so the 4 gate fragments share one pointer + imm offsets):
//   idx = ((ntL*33 + kt)*4 + g)*512 + lanep*8 + ks
//   with n = g*512 + ntL*32 + ni, g=n>>9, ntL=(n>>5)&15, ni=n&31,
//        kt=ka>>4, kh=(ka>>3)&1, ks=ka&7, lanep=kh*32+ni
__global__ void prep_weights(
    const float* __restrict__ Wh_s, const float* __restrict__ Wi_s, const float* __restrict__ b_s,
    const float* __restrict__ Wh_p, const float* __restrict__ Wi_p, const float* __restrict__ b_p,
    const float* __restrict__ Wh_d, const float* __restrict__ Wi_d, const float* __restrict__ b_d,
    const float* __restrict__ Wh_i, const float* __restrict__ Wi_i, const float* __restrict__ b_i,
    short* __restrict__ wpack)
{
  int idx = blockIdx.x * 256 + threadIdx.x;
  const int per = 2048 * KAUG;
  if (idx >= 4 * per) return;
  int mat = idx / per;
  int rem = idx - mat * per;
  int n = rem / KAUG;
  int ka = rem - n * KAUG;
  const float* Wh; const float* Wi; const float* bb;
  if (mat == 0)      { Wh = Wh_s; Wi = Wi_s; bb = b_s; }
  else if (mat == 1) { Wh = Wh_p; Wi = Wi_p; bb = b_p; }
  else if (mat == 2) { Wh = Wh_d; Wi = Wi_d; bb = b_d; }
  else               { Wh = Wh_i; Wi = Wi_i; bb = b_i; }
  float v;
  if (ka < 512)      v = Wh[n * 512 + ka];
  else if (ka < 516) v = Wi[n * 4 + (ka - 512)];
  else if (ka == 516) v = bb[n];
  else               v = 0.0f;
  int g = n >> 9, ntL = (n >> 5) & 15, ni = n & 31;
  int kt = ka >> 4, kh = (ka >> 3) & 1, ks = ka & 7;
  int lanep = kh * 32 + ni;
  wpack[(size_t)mat * WMAT_ELEMS +
        (((((size_t)ntL * KT_N + kt) * 4 + g) << 9) + (lanep << 3) + ks)] = (short)f2bf(v);
}

// ---------------- one LSTM step: gates = h_aug @ W_aug.T, then cell update ---
// wave wv owns h-cols [wv*64, wv*64+64); computes all 4 gates for that slice.
__device__ __forceinline__ void lstm_step_mfma(
    const short* hl, const short* __restrict__ wm,
    int lane, int wv, float c_reg[2][16], float hnew[2][16])
{
  int arow = lane & 31, ahalf = lane >> 5;
  const short* aptr = hl + arow * LROW + ahalf * 8;
  #pragma unroll
  for (int jt = 0; jt < 2; ++jt) {
    int ntL = wv * 2 + jt;
    const short* bp = wm + (size_t)ntL * (KT_N * 4 * 512) + (lane << 3);
    floatx16 ai = (floatx16)0.0f, af = (floatx16)0.0f, ag = (floatx16)0.0f, ao = (floatx16)0.0f;
    #pragma unroll 3
    for (int kt = 0; kt < KT_N; ++kt) {
      short8 a  = *(const short8*)(aptr + kt * 16);
      short8 b0 = *(const short8*)(bp);          // gate i   (+0    B)
      short8 b1 = *(const short8*)(bp + 512);    // gate f   (+1024 B, imm)
      short8 b2 = *(const short8*)(bp + 1024);   // gate g   (+2048 B, imm)
      short8 b3 = *(const short8*)(bp + 1536);   // gate o   (+3072 B, imm)
      bp += 2048;
      ai = __builtin_amdgcn_mfma_f32_32x32x16_bf16(a, b0, ai, 0, 0, 0);
      af = __builtin_amdgcn_mfma_f32_32x32x16_bf16(a, b1, af, 0, 0, 0);
      ag = __builtin_amdgcn_mfma_f32_32x32x16_bf16(a, b2, ag, 0, 0, 0);
      ao = __builtin_amdgcn_mfma_f32_32x32x16_bf16(a, b3, ao, 0, 0, 0);
    }
    #pragma unroll
    for (int r = 0; r < 16; ++r) {
      float si = sigm(ai[r]);
      float sf = sigm(af[r]);
      float tg = tanh_f(ag[r]);
      float so = sigm(ao[r]);
      float cn = sf * c_reg[jt][r] + si * tg;
      c_reg[jt][r] = cn;
      hnew[jt][r] = so * tanh_f(cn);
    }
  }
}

__device__ __forceinline__ void write_h(short* hl, int lane, int wv, const float hnew[2][16]) {
  int arow = lane & 31, ahalf = lane >> 5;
  #pragma unroll
  for (int jt = 0; jt < 2; ++jt) {
    int col = wv * 64 + jt * 32 + arow;
    #pragma unroll
    for (int r = 0; r < 16; ++r) {
      int row = (r & 3) + ((r >> 2) << 3) + (ahalf << 2);
      hl[row * LROW + col] = (short)f2bf(hnew[jt][r]);
    }
  }
}

// ---------------- encoder: blocks 0..255 -> (enc, row-group) via XCD swizzle --
__global__ __launch_bounds__(512) void lstm_encoder(
    const float* __restrict__ speed, const float* __restrict__ pos,
    const short* __restrict__ wpack,
    short* __restrict__ h_enc, float* __restrict__ c_enc)
{
  __shared__ short hl[NROW * LROW];
  int tid = threadIdx.x;
  int b = blockIdx.x;
  int xcd = b & 7, slot = b >> 3;
  int enc = xcd >> 2;               // XCDs 0-3: speed, 4-7: pos (L2 locality)
  int rg = slot * 4 + (xcd & 3);    // 0..127
  int r0 = rg * 32;
  const float* xin = enc ? pos : speed;
  const short* wm = wpack + (size_t)enc * WMAT_ELEMS;

  for (int i = tid; i < NROW * LROW; i += 512) hl[i] = 0;
  __syncthreads();
  if (tid < 32) hl[tid * LROW + 516] = (short)0x3F80;   // bias lane = 1.0
  if (tid < 128) {
    int r = tid >> 2, c = tid & 3;
    hl[r * LROW + 512 + c] = (short)f2bf(xin[(r0 + r) * 64 + c]);   // x_0
  }
  __syncthreads();

  int lane = tid & 63, wv = tid >> 6;
  float c_reg[2][16];
  #pragma unroll
  for (int jt = 0; jt < 2; ++jt)
    #pragma unroll
    for (int r = 0; r < 16; ++r) c_reg[jt][r] = 0.0f;
  float hnew[2][16];

  for (int t = 0; t < 16; ++t) {
    lstm_step_mfma(hl, wm, lane, wv, c_reg, hnew);
    __syncthreads();
    write_h(hl, lane, wv, hnew);
    if (t < 15 && tid < 128) {
      int r = tid >> 2, c = tid & 3;
      hl[r * LROW + 512 + c] = (short)f2bf(xin[(r0 + r) * 64 + (t + 1) * 4 + c]);
    }
    __syncthreads();
  }

  // store h (bf16) + c (fp32) for the decoder
  for (int i = tid; i < 32 * 512; i += 512) {
    int r = i >> 9, k = i & 511;
    h_enc[((size_t)(enc * B_TOT + r0 + r) << 9) + k] = hl[r * LROW + k];
  }
  int arow = lane & 31, ahalf = lane >> 5;
  #pragma unroll
  for (int jt = 0; jt < 2; ++jt) {
    int col = wv * 64 + jt * 32 + arow;
    #pragma unroll
    for (int r = 0; r < 16; ++r) {
      int row = (r & 3) + ((r >> 2) << 3) + (ahalf << 2);
      c_enc[((size_t)(enc * B_TOT + r0 + row) << 9) + col] = c_reg[jt][r];
    }
  }
}

// ---------------- decoder: chain 0 = speed head, chain 1 = crossing head -----
__global__ __launch_bounds__(512) void lstm_decoder(
    const float* __restrict__ speed, const float* __restrict__ pos,
    const short* __restrict__ wpack,
    const short* __restrict__ h_enc, const float* __restrict__ c_enc,
    const float* __restrict__ W_fs, const float* __restrict__ b_fs,
    const float* __restrict__ W_fc, const float* __restrict__ b_fc,
    const float* __restrict__ W_emb, const float* __restrict__ b_emb,
    float* __restrict__ out)
{
  __shared__ short hl[NROW * LROW];
  int tid = threadIdx.x;
  int b = blockIdx.x;
  int xcd = b & 7, slot = b >> 3;
  int chain = xcd >> 2;
  int rg = slot * 4 + (xcd & 3);
  int r0 = rg * 32;
  const short* wm = wpack + (size_t)(2 + chain) * WMAT_ELEMS;

  for (int i = tid; i < NROW * LROW; i += 512) hl[i] = 0;
  __syncthreads();
  for (int i = tid; i < 32 * 512; i += 512) {
    int r = i >> 9, k = i & 511;
    float h0 = bf2f((unsigned short)h_enc[((size_t)(r0 + r) << 9) + k])
             + bf2f((unsigned short)h_enc[((size_t)(B_TOT + r0 + r) << 9) + k]);
    hl[r * LROW + k] = (short)f2bf(h0);
  }
  if (tid < 32) hl[tid * LROW + 516] = (short)0x3F80;
  {
    const float* last = chain ? pos : speed;
    if (tid < 128) {
      int r = tid >> 2, c = tid & 3;
      hl[r * LROW + 512 + c] = (short)f2bf(last[(r0 + r) * 64 + 60 + c]); // x[:,15,:]
    }
  }
  int lane = tid & 63, wv = tid >> 6;
  int arow = lane & 31, ahalf = lane >> 5;
  float c_reg[2][16];
  #pragma unroll
  for (int jt = 0; jt < 2; ++jt) {
    int col = wv * 64 + jt * 32 + arow;
    #pragma unroll
    for (int r = 0; r < 16; ++r) {
      int row = (r & 3) + ((r >> 2) << 3) + (ahalf << 2);
      size_t gi = ((size_t)(r0 + row) << 9) + col;
      c_reg[jt][r] = c_enc[gi] + c_enc[gi + (((size_t)B_TOT) << 9)];
    }
  }
  __syncthreads();

  // preload head weights (per-lane 8-elem slice of each output row)
  float wro[4][8];
  float hb[4];
  float we[8], be[4];
  if (chain == 0) {
    #pragma unroll
    for (int o = 0; o < 4; ++o) {
      #pragma unroll
      for (int j = 0; j < 8; ++j) wro[o][j] = W_fs[o * 512 + lane * 8 + j];
      hb[o] = b_fs[o];
    }
  } else {
    #pragma unroll
    for (int o = 0; o < 2; ++o) {
      #pragma unroll
      for (int j = 0; j < 8; ++j) wro[o][j] = W_fc[o * 512 + lane * 8 + j];
      hb[o] = b_fc[o];
    }
    #pragma unroll
    for (int j = 0; j < 8; ++j) we[j] = W_emb[j];
    #pragma unroll
    for (int o = 0; o < 4; ++o) be[o] = b_emb[o];
  }

  float hnew[2][16];
  for (int t = 0; t < T_DEC; ++t) {
    lstm_step_mfma(hl, wm, lane, wv, c_reg, hnew);
    __syncthreads();
    write_h(hl, lane, wv, hnew);
    __syncthreads();
    // heads: wave wv handles rows [wv*4, wv*4+4); 64 lanes x 8 k-elems = 512
    #pragma unroll 1
    for (int r = 0; r < 4; ++r) {
      int row = wv * 4 + r;
      const short8 hvs = *(const short8*)(hl + row * LROW + lane * 8);
      float hv[8];
      #pragma unroll
      for (int j = 0; j < 8; ++j) hv[j] = bf2f((unsigned short)hvs[j]);
      if (chain == 0) {
        float p0 = 0.f, p1 = 0.f, p2 = 0.f, p3 = 0.f;
        #pragma unroll
        for (int j = 0; j < 8; ++j) {
          p0 += hv[j] * wro[0][j];
          p1 += hv[j] * wro[1][j];
          p2 += hv[j] * wro[2][j];
          p3 += hv[j] * wro[3][j];
        }
        #pragma unroll
        for (int off = 32; off > 0; off >>= 1) {
          p0 += __shfl_xor(p0, off);
          p1 += __shfl_xor(p1, off);
          p2 += __shfl_xor(p2, off);
          p3 += __shfl_xor(p3, off);
        }
        float s0 = fminf(fmaxf(p0 + hb[0], -100.0f), 100.0f);
        float s1 = fminf(fmaxf(p1 + hb[1], -100.0f), 100.0f);
        float s2 = fminf(fmaxf(p2 + hb[2], -100.0f), 100.0f);
        float s3 = fminf(fmaxf(p3 + hb[3], -100.0f), 100.0f);
        if (lane < 4) {
          float v = (lane == 0) ? s0 : (lane == 1) ? s1 : (lane == 2) ? s2 : s3;
          out[(size_t)(r0 + row) * 128 + t * 4 + lane] = v;       // speed_outputs
          hl[row * LROW + 512 + lane] = (short)f2bf(v);           // ls feedback
        }
      } else {
        float p0 = 0.f, p1 = 0.f;
        #pragma unroll
        for (int j = 0; j < 8; ++j) {
          p0 += hv[j] * wro[0][j];
          p1 += hv[j] * wro[1][j];
        }
        #pragma unroll
        for (int off = 32; off > 0; off >>= 1) {
          p0 += __shfl_xor(p0, off);
          p1 += __shfl_xor(p1, off);
        }
        float it0 = fmaxf(p0 + hb[0], 0.0f);
        float it1 = fmaxf(p1 + hb[1], 0.0f);
        if (lane < 4) {
          float lp = fmaxf(we[lane * 2] * it0 + we[lane * 2 + 1] * it1 + be[lane], 0.0f);
          hl[row * LROW + 512 + lane] = (short)f2bf(lp);          // lp feedback
        }
        if (t == T_DEC - 1 && lane < 2) {
          float m = fmaxf(it0, it1);
          float e0 = __expf(it0 - m), e1 = __expf(it1 - m);
          float v = ((lane == 0) ? e0 : e1) * rcpf(e0 + e1);
          out[(size_t)524288 + (size_t)(r0 + row) * 2 + lane] = v; // crossing
        }
      }
    }
    __syncthreads();
  }
}

extern "C" void kernel_launch(void* const* d_in, const int* in_sizes, int n_in,
                              void* d_out, int out_size, void* d_ws, size_t ws_size,
                              hipStream_t stream)
{
  const float* speed    = (const float*)d_in[0];
  const float* pos      = (const float*)d_in[1];
  const float* enc_s_Wi = (const float*)d_in[2];
  const float* enc_s_Wh = (const float*)d_in[3];
  const float* enc_s_b  = (const float*)d_in[4];
  const float* enc_p_Wi = (const float*)d_in[5];
  const float* enc_p_Wh = (const float*)d_in[6];
  const float* enc_p_b  = (const float*)d_in[7];
  const float* dec_s_Wi = (const float*)d_in[8];
  const float* dec_s_Wh = (const float*)d_in[9];
  const float* dec_s_b  = (const float*)d_in[10];
  const float* dec_i_Wi = (const float*)d_in[11];
  const float* dec_i_Wh = (const float*)d_in[12];
  const float* dec_i_b  = (const float*)d_in[13];
  const float* W_fs     = (const float*)d_in[14];
  const float* b_fs     = (const float*)d_in[15];
  const float* W_fc     = (const float*)d_in[16];
  const float* b_fc     = (const float*)d_in[17];
  const float* W_emb    = (const float*)d_in[18];
  const float* b_emb    = (const float*)d_in[19];
  float* out = (float*)d_out;

  char* ws = (char*)d_ws;
  short* wpack = (short*)ws;                 // 4 x 2,162,688 B = 8,650,752 B
  short* h_enc = (short*)(ws + 8650752);     // 2 x 4096 x 512 bf16 = 8,388,608 B
  float* c_enc = (float*)(ws + 17039360);    // 2 x 4096 x 512 f32  = 16,777,216 B

  prep_weights<<<16896, 256, 0, stream>>>(
      enc_s_Wh, enc_s_Wi, enc_s_b,
      enc_p_Wh, enc_p_Wi, enc_p_b,
      dec_s_Wh, dec_s_Wi, dec_s_b,
      dec_i_Wh, dec_i_Wi, dec_i_b,
      wpack);
  lstm_encoder<<<256, 512, 0, stream>>>(speed, pos, wpack, h_enc, c_enc);
  lstm_decoder<<<256, 512, 0, stream>>>(speed, pos, wpack, h_enc, c_enc,
                                        W_fs, b_fs, W_fc, b_fc, W_emb, b_emb, out);
}